// Round 1
// baseline (279.543 us; speedup 1.0000x reference)
//
#include <hip/hip_runtime.h>

// PillarVFE fused pipeline: feature-gen + 10->64 matmul + global BN + relu + max over P.
// BN stats via feature first/second moments (65 scalars) -> no x materialization.

namespace {
constexpr int V_    = 100000;
constexpr int P_    = 32;
constexpr int COUT  = 64;
constexpr int NF    = 10;
constexpr int NMOM  = 65;     // 10 sums + 55 upper-triangular second moments
constexpr int PSTRIDE = 72;   // padded partial row stride (floats)
constexpr int K1_BLOCKS = 512;
constexpr int NWAVES = K1_BLOCKS * 4;  // 2048 wave partial slots

constexpr float VX_ = 0.16f, VY_ = 0.16f, VZ_ = 4.0f;
constexpr float XOFF_ = 0.16f / 2 + 0.0f;     //  0.08
constexpr float YOFF_ = 0.16f / 2 - 39.68f;   // -39.60
constexpr float ZOFF_ = 4.0f / 2 - 3.0f;      // -1.00
constexpr float EPS_ = 0.001f;
}

// lane = point within a 32-lane half-wave; computes the 10 masked features.
__device__ __forceinline__ void compute_features(
    const float4 pt, int cnt, int4 cd, int p, bool vvalid, float f[NF])
{
  // points_mean = sum over ALL 32 points / cnt (reference sums all P rows)
  float sx = pt.x, sy = pt.y, sz = pt.z;
  #pragma unroll
  for (int m = 16; m >= 1; m >>= 1) {
    sx += __shfl_xor(sx, m, 32);
    sy += __shfl_xor(sy, m, 32);
    sz += __shfl_xor(sz, m, 32);
  }
  float cf = (float)cnt;
  float mx = sx / cf, my = sy / cf, mz = sz / cf;
  // coords columns: [bidx, zc, yc, xc]
  float cx = (float)cd.w * VX_ + XOFF_;
  float cy = (float)cd.z * VY_ + YOFF_;
  float cz = (float)cd.y * VZ_ + ZOFF_;
  float msk = (vvalid && (p < cnt)) ? 1.0f : 0.0f;
  f[0] = pt.x * msk;
  f[1] = pt.y * msk;
  f[2] = pt.z * msk;
  f[3] = pt.w * msk;
  f[4] = (pt.x - mx) * msk;
  f[5] = (pt.y - my) * msk;
  f[6] = (pt.z - mz) * msk;
  f[7] = (pt.x - cx) * msk;
  f[8] = (pt.y - cy) * msk;
  f[9] = (pt.z - cz) * msk;
}

// Pass 1: accumulate sum(f) [10] and upper-tri sum(f f^T) [55] per wave.
__global__ __launch_bounds__(256) void k1_stats(
    const float* __restrict__ vf, const int* __restrict__ npts,
    const int* __restrict__ coords, float* __restrict__ partials)
{
  float acc[NMOM];
  #pragma unroll
  for (int i = 0; i < NMOM; ++i) acc[i] = 0.f;

  const int tid = threadIdx.x;
  const int sub = tid >> 5;   // voxel slot within block (0..7)
  const int p   = tid & 31;   // point index

  for (int base = blockIdx.x * 8; base < V_; base += K1_BLOCKS * 8) {
    int v = base + sub;
    bool vvalid = (v < V_);
    float4 pt = make_float4(0.f, 0.f, 0.f, 0.f);
    int cnt = 1;
    int4 cd = make_int4(0, 0, 0, 0);
    if (vvalid) {
      pt  = ((const float4*)vf)[v * P_ + p];   // coalesced 16B/lane
      cnt = npts[v];
      cd  = ((const int4*)coords)[v];
    }
    float f[NF];
    compute_features(pt, cnt, cd, p, vvalid, f);
    #pragma unroll
    for (int c = 0; c < NF; ++c) acc[c] += f[c];
    int idx = NF;
    #pragma unroll
    for (int c = 0; c < NF; ++c)
      #pragma unroll
      for (int c2 = c; c2 < NF; ++c2)
        acc[idx++] += f[c] * f[c2];
  }

  // butterfly reduce across the 64-lane wave
  #pragma unroll
  for (int i = 0; i < NMOM; ++i) {
    float a = acc[i];
    #pragma unroll
    for (int m = 32; m >= 1; m >>= 1) a += __shfl_xor(a, m, 64);
    acc[i] = a;
  }
  if ((tid & 63) == 0) {
    int waveId = blockIdx.x * 4 + (tid >> 6);
    float* dst = partials + waveId * PSTRIDE;
    #pragma unroll
    for (int i = 0; i < NMOM; ++i) dst[i] = acc[i];
  }
}

// Pass 2: reduce 2048 partials (double), derive per-channel affine a,b.
__global__ __launch_bounds__(128) void k2_finalize(
    const float* __restrict__ partials, const float* __restrict__ Wm,
    const float* __restrict__ gamma, const float* __restrict__ beta,
    float* __restrict__ ab)
{
  __shared__ double S[NMOM];
  const int t = threadIdx.x;
  if (t < NMOM) {
    double a0 = 0, a1 = 0, a2 = 0, a3 = 0;
    for (int w = 0; w < NWAVES; w += 4) {
      a0 += (double)partials[(w + 0) * PSTRIDE + t];
      a1 += (double)partials[(w + 1) * PSTRIDE + t];
      a2 += (double)partials[(w + 2) * PSTRIDE + t];
      a3 += (double)partials[(w + 3) * PSTRIDE + t];
    }
    S[t] = (a0 + a1) + (a2 + a3);
  }
  __syncthreads();
  if (t < COUT) {
    const double N = (double)V_ * (double)P_;
    double w[NF];
    #pragma unroll
    for (int c = 0; c < NF; ++c) w[c] = (double)Wm[t * NF + c];
    double mean = 0.0;
    #pragma unroll
    for (int c = 0; c < NF; ++c) mean += w[c] * S[c];
    mean /= N;
    double ex2 = 0.0;
    int idx = NF;
    #pragma unroll
    for (int c = 0; c < NF; ++c)
      #pragma unroll
      for (int c2 = c; c2 < NF; ++c2) {
        double coef = (c == c2) ? 1.0 : 2.0;
        ex2 += coef * w[c] * w[c2] * S[idx++];
      }
    ex2 /= N;
    double var = ex2 - mean * mean;
    double rs = 1.0 / sqrt(var + (double)EPS_);
    double a = (double)gamma[t] * rs;
    double b = (double)beta[t] - mean * a;
    ab[t] = (float)a;
    ab[COUT + t] = (float)b;
  }
}

// Pass 3: recompute features -> LDS, then per-(voxel, channel) dot + affine + relu + max_P.
__global__ __launch_bounds__(256) void k3_out(
    const float* __restrict__ vf, const int* __restrict__ npts,
    const int* __restrict__ coords, const float* __restrict__ Wm,
    const float* __restrict__ ab, float* __restrict__ out)
{
  __shared__ float fs[8 * 32 * 11];   // 8 voxels x 32 pts x 10 feats, stride 11 (bank-clean)
  const int tid = threadIdx.x;
  const int vbase = blockIdx.x * 8;

  { // Phase A: lane = point
    const int sub = tid >> 5;
    const int p = tid & 31;
    int v = vbase + sub;
    bool vvalid = (v < V_);
    float4 pt = make_float4(0.f, 0.f, 0.f, 0.f);
    int cnt = 1;
    int4 cd = make_int4(0, 0, 0, 0);
    if (vvalid) {
      pt  = ((const float4*)vf)[v * P_ + p];
      cnt = npts[v];
      cd  = ((const int4*)coords)[v];
    }
    float f[NF];
    compute_features(pt, cnt, cd, p, vvalid, f);
    float* row = &fs[(sub * 32 + p) * 11];
    #pragma unroll
    for (int c = 0; c < NF; ++c) row[c] = f[c];
  }
  __syncthreads();

  // Phase B: wave = one voxel, lane = output channel; LDS reads are wave-broadcast.
  const int o = tid & 63;
  float wr[NF];
  #pragma unroll
  for (int c = 0; c < NF; ++c) wr[c] = Wm[o * NF + c];
  const float a = ab[o];
  const float b = ab[COUT + o];

  #pragma unroll
  for (int it = 0; it < 2; ++it) {
    int g = it * 4 + (tid >> 6);
    int v = vbase + g;
    if (v < V_) {
      float mmax = 0.f;   // relu folded: max(0, max_p y_p)
      const float* fp = &fs[g * 32 * 11];
      #pragma unroll 4
      for (int pp = 0; pp < 32; ++pp) {
        const float* fr = fp + pp * 11;
        float dot = fr[0] * wr[0];
        #pragma unroll
        for (int c = 1; c < NF; ++c) dot = fmaf(fr[c], wr[c], dot);
        float y = fmaf(a, dot, b);
        mmax = fmaxf(mmax, y);
      }
      out[v * COUT + o] = mmax;   // consecutive o -> coalesced
    }
  }
}

extern "C" void kernel_launch(void* const* d_in, const int* in_sizes, int n_in,
                              void* d_out, int out_size, void* d_ws, size_t ws_size,
                              hipStream_t stream)
{
  const float* vf     = (const float*)d_in[0];
  const int*   npts   = (const int*)d_in[1];
  const int*   coords = (const int*)d_in[2];
  const float* Wm     = (const float*)d_in[3];
  const float* gamma  = (const float*)d_in[4];
  const float* beta   = (const float*)d_in[5];
  float* out = (float*)d_out;

  float* ws = (float*)d_ws;
  float* partials = ws;                       // NWAVES * PSTRIDE floats (all written each call)
  float* ab = ws + NWAVES * PSTRIDE;          // 128 floats

  k1_stats<<<K1_BLOCKS, 256, 0, stream>>>(vf, npts, coords, partials);
  k2_finalize<<<1, 128, 0, stream>>>(partials, Wm, gamma, beta, ab);
  const int nb3 = (V_ + 7) / 8;
  k3_out<<<nb3, 256, 0, stream>>>(vf, npts, coords, Wm, ab, out);
}

// Round 2
// 162.220 us; speedup vs baseline: 1.7232x; 1.7232x over previous
//
#include <hip/hip_runtime.h>
#include <hip/hip_bf16.h>

// PillarVFE fused: feature-gen + 10->64 matmul (bf16 MFMA) + global BN + relu + max over P.
// BN stats via feature first/second moments (65 scalars) -> x never materialized.

typedef __attribute__((ext_vector_type(8))) short short8;     // 8 bf16 (4 VGPRs)
typedef __attribute__((ext_vector_type(16))) float floatx16;  // 32x32 MFMA C/D

namespace {
constexpr int V_    = 100000;
constexpr int P_    = 32;
constexpr int COUT  = 64;
constexpr int NF    = 10;
constexpr int NMOM  = 65;     // 10 sums + 55 upper-tri second moments
constexpr int PSTRIDE = 72;   // padded partial row stride (floats)
constexpr int K1_BLOCKS = 512;
constexpr int K3_BLOCKS = 1536;  // 6144 waves, ~16 voxels/wave

constexpr float VX_ = 0.16f, VY_ = 0.16f, VZ_ = 4.0f;
constexpr float XOFF_ = 0.08f, YOFF_ = -39.60f, ZOFF_ = -1.0f;
constexpr float EPS_ = 0.001f;
}

__device__ __forceinline__ short f2bf(float x) {  // RNE, finite inputs
  unsigned u = __builtin_bit_cast(unsigned, x);
  u += 0x7fffu + ((u >> 16) & 1u);
  return (short)(u >> 16);
}

// lane(&31) = point; computes the 10 masked features (mean via width-32 butterfly).
__device__ __forceinline__ void compute_features(
    const float4 pt, int cnt, int4 cd, int p, float f[NF])
{
  float sx = pt.x, sy = pt.y, sz = pt.z;
  #pragma unroll
  for (int m = 16; m >= 1; m >>= 1) {
    sx += __shfl_xor(sx, m, 32);
    sy += __shfl_xor(sy, m, 32);
    sz += __shfl_xor(sz, m, 32);
  }
  float cf = (float)cnt;
  float mx = sx / cf, my = sy / cf, mz = sz / cf;
  float cx = (float)cd.w * VX_ + XOFF_;
  float cy = (float)cd.z * VY_ + YOFF_;
  float cz = (float)cd.y * VZ_ + ZOFF_;
  float msk = (p < cnt) ? 1.0f : 0.0f;
  f[0] = pt.x * msk;
  f[1] = pt.y * msk;
  f[2] = pt.z * msk;
  f[3] = pt.w * msk;
  f[4] = (pt.x - mx) * msk;
  f[5] = (pt.y - my) * msk;
  f[6] = (pt.z - mz) * msk;
  f[7] = (pt.x - cx) * msk;
  f[8] = (pt.y - cy) * msk;
  f[9] = (pt.z - cz) * msk;
}

// Pass 1: per-wave 65 moment accumulators -> block-level LDS reduce -> 512 partial rows.
__global__ __launch_bounds__(256) void k1_stats(
    const float* __restrict__ vf, const int* __restrict__ npts,
    const int* __restrict__ coords, float* __restrict__ partials)
{
  float acc[NMOM];
  #pragma unroll
  for (int i = 0; i < NMOM; ++i) acc[i] = 0.f;

  const int tid = threadIdx.x;
  const int sub = tid >> 5;   // voxel slot within block (0..7)
  const int p   = tid & 31;

  for (int base = blockIdx.x * 8; base < V_; base += K1_BLOCKS * 8) {
    int v = base + sub;
    bool vvalid = (v < V_);
    float4 pt = make_float4(0.f, 0.f, 0.f, 0.f);
    int cnt = P_ + 1;   // mask=0 for all p not needed; use real mask below
    int4 cd = make_int4(0, 0, 0, 0);
    if (vvalid) {
      pt  = ((const float4*)vf)[v * P_ + p];
      cnt = npts[v];
      cd  = ((const int4*)coords)[v];
    } else {
      cnt = 0;          // masks every point of invalid voxel slot
    }
    float f[NF];
    compute_features(pt, cnt == 0 ? 1 : cnt, cd, cnt == 0 ? 32 : p, f);
    if (cnt == 0) {
      #pragma unroll
      for (int c = 0; c < NF; ++c) f[c] = 0.f;
    }
    #pragma unroll
    for (int c = 0; c < NF; ++c) acc[c] += f[c];
    int idx = NF;
    #pragma unroll
    for (int c = 0; c < NF; ++c)
      #pragma unroll
      for (int c2 = c; c2 < NF; ++c2)
        acc[idx++] += f[c] * f[c2];
  }

  // 64-lane butterfly per moment
  #pragma unroll
  for (int i = 0; i < NMOM; ++i) {
    float a = acc[i];
    #pragma unroll
    for (int m = 32; m >= 1; m >>= 1) a += __shfl_xor(a, m, 64);
    acc[i] = a;
  }

  __shared__ float red[4][NMOM];
  if ((tid & 63) == 0) {
    int w = tid >> 6;
    #pragma unroll
    for (int i = 0; i < NMOM; ++i) red[w][i] = acc[i];
  }
  __syncthreads();
  if (tid < NMOM) {
    partials[blockIdx.x * PSTRIDE + tid] =
        (red[0][tid] + red[1][tid]) + (red[2][tid] + red[3][tid]);
  }
}

// Pass 2: parallel reduce 512 partial rows, derive per-channel affine a,b.
__global__ __launch_bounds__(576) void k2_finalize(
    const float* __restrict__ partials, const float* __restrict__ Wm,
    const float* __restrict__ gamma, const float* __restrict__ beta,
    float* __restrict__ ab)
{
  __shared__ float s1[8 * NMOM];
  __shared__ double S[NMOM];
  const int t = threadIdx.x;

  if (t < 8 * NMOM) {
    int col = t % NMOM, chunk = t / NMOM;   // 8 chunks x 64 rows
    float acc = 0.f;
    int base = chunk * 64;
    #pragma unroll 4
    for (int i = 0; i < 64; ++i) acc += partials[(base + i) * PSTRIDE + col];
    s1[chunk * NMOM + col] = acc;
  }
  __syncthreads();
  if (t < NMOM) {
    double d = 0.0;
    #pragma unroll
    for (int c = 0; c < 8; ++c) d += (double)s1[c * NMOM + t];
    S[t] = d;
  }
  __syncthreads();
  if (t < COUT) {
    const double N = (double)V_ * (double)P_;
    double w[NF];
    #pragma unroll
    for (int c = 0; c < NF; ++c) w[c] = (double)Wm[t * NF + c];
    double mean = 0.0;
    #pragma unroll
    for (int c = 0; c < NF; ++c) mean += w[c] * S[c];
    mean /= N;
    double ex2 = 0.0;
    int idx = NF;
    #pragma unroll
    for (int c = 0; c < NF; ++c)
      #pragma unroll
      for (int c2 = c; c2 < NF; ++c2) {
        double coef = (c == c2) ? 1.0 : 2.0;
        ex2 += coef * w[c] * w[c2] * S[idx++];
      }
    ex2 /= N;
    double var = ex2 - mean * mean;
    double rs = 1.0 / sqrt(var + (double)EPS_);
    double a = (double)gamma[t] * rs;
    double b = (double)beta[t] - mean * a;
    ab[t] = (float)a;
    ab[COUT + t] = (float)b;
  }
}

// Pass 3: one wave = one voxel per iter. A-frag in regs, 2x mfma_32x32x16_bf16,
// epilogue via max/min + sign-of-a trick (relu(a*x+b) monotone in x).
__global__ __launch_bounds__(256) void k3_mfma(
    const float* __restrict__ vf, const int* __restrict__ npts,
    const int* __restrict__ coords, const float* __restrict__ Wm,
    const float* __restrict__ ab, float* __restrict__ out)
{
  const int tid  = threadIdx.x;
  const int lane = tid & 63;
  const int p    = lane & 31;   // point (A rows) / channel-in-group (B cols)
  const int half = lane >> 5;   // k-half: half*8 + j
  const int waveG = blockIdx.x * 4 + (tid >> 6);
  const int nW = K3_BLOCKS * 4;

  // Persistent B fragments: B[k][n], n = lane&31 (channel in group), k = half*8+j
  short8 bf0, bf1;
  #pragma unroll
  for (int j = 0; j < 8; ++j) {
    int k = half * 8 + j;
    float w0 = (k < NF) ? Wm[p * NF + k] : 0.f;
    float w1 = (k < NF) ? Wm[(32 + p) * NF + k] : 0.f;
    bf0[j] = f2bf(w0);
    bf1[j] = f2bf(w1);
  }
  const float a0 = ab[p],      b0 = ab[COUT + p];
  const float a1 = ab[32 + p], b1 = ab[COUT + 32 + p];

  for (int v = waveG; v < V_; v += nW) {
    float4 pt = ((const float4*)vf)[v * P_ + p];  // halves load same 512B (L1 dedupe)
    int cnt = npts[v];
    int4 cd = ((const int4*)coords)[v];
    float f[NF];
    compute_features(pt, cnt, cd, p, f);

    // A fragment: A[m=lane&31][k=half*8+j]; only k<10 real.
    float av[8];
    #pragma unroll
    for (int j = 0; j < 8; ++j) av[j] = f[j];
    if (half) {
      av[0] = f[8]; av[1] = f[9];
      #pragma unroll
      for (int j = 2; j < 8; ++j) av[j] = 0.f;
    }
    short8 af;
    #pragma unroll
    for (int j = 0; j < 8; ++j) af[j] = f2bf(av[j]);

    floatx16 c0, c1;
    #pragma unroll
    for (int i = 0; i < 16; ++i) { c0[i] = 0.f; c1[i] = 0.f; }
    c0 = __builtin_amdgcn_mfma_f32_32x32x16_bf16(af, bf0, c0, 0, 0, 0);
    c1 = __builtin_amdgcn_mfma_f32_32x32x16_bf16(af, bf1, c1, 0, 0, 0);

    // max & min over this lane's 16 rows, then combine complementary rows (lane^32)
    float mx0 = c0[0], mn0 = c0[0], mx1 = c1[0], mn1 = c1[0];
    #pragma unroll
    for (int i = 1; i < 16; ++i) {
      mx0 = fmaxf(mx0, c0[i]); mn0 = fminf(mn0, c0[i]);
      mx1 = fmaxf(mx1, c1[i]); mn1 = fminf(mn1, c1[i]);
    }
    mx0 = fmaxf(mx0, __shfl_xor(mx0, 32, 64));
    mn0 = fminf(mn0, __shfl_xor(mn0, 32, 64));
    mx1 = fmaxf(mx1, __shfl_xor(mx1, 32, 64));
    mn1 = fminf(mn1, __shfl_xor(mn1, 32, 64));

    float y0 = fmaxf(fmaf(a0, (a0 >= 0.f) ? mx0 : mn0, b0), 0.f);
    float y1 = fmaxf(fmaf(a1, (a1 >= 0.f) ? mx1 : mn1, b1), 0.f);
    out[v * COUT + lane] = half ? y1 : y0;   // lane = half*32+p -> coalesced
  }
}

extern "C" void kernel_launch(void* const* d_in, const int* in_sizes, int n_in,
                              void* d_out, int out_size, void* d_ws, size_t ws_size,
                              hipStream_t stream)
{
  const float* vf     = (const float*)d_in[0];
  const int*   npts   = (const int*)d_in[1];
  const int*   coords = (const int*)d_in[2];
  const float* Wm     = (const float*)d_in[3];
  const float* gamma  = (const float*)d_in[4];
  const float* beta   = (const float*)d_in[5];
  float* out = (float*)d_out;

  float* ws = (float*)d_ws;
  float* partials = ws;                          // K1_BLOCKS * PSTRIDE floats
  float* ab = ws + K1_BLOCKS * PSTRIDE;          // 128 floats

  k1_stats<<<K1_BLOCKS, 256, 0, stream>>>(vf, npts, coords, partials);
  k2_finalize<<<1, 576, 0, stream>>>(partials, Wm, gamma, beta, ab);
  k3_mfma<<<K3_BLOCKS, 256, 0, stream>>>(vf, npts, coords, Wm, ab, out);
}